// Round 7
// baseline (166.690 us; speedup 1.0000x reference)
//
#include <hip/hip_runtime.h>
#include <hip/hip_bf16.h>

#define B_   2
#define T_   2048
#define HID_ 1024
#define NH_  16
#define HD_  64
#define K_   1024
#define M_   (B_*T_)

typedef __attribute__((ext_vector_type(8)))  short bf16x8;
typedef __attribute__((ext_vector_type(4)))  float f32x4;
typedef __attribute__((ext_vector_type(16))) float f32x16;
typedef __attribute__((ext_vector_type(4)))  unsigned int u32x4;

#define LOG2E 1.44269504088896340736f

__device__ inline unsigned short f2bf(float f) {
    __hip_bfloat16 h = __float2bfloat16(f);
    return __builtin_bit_cast(unsigned short, h);
}
__device__ inline float bf2f(unsigned short u) {
    return __builtin_bit_cast(float, (unsigned int)u << 16);
}
__device__ inline unsigned int pk2(float a, float b) {
    return (unsigned int)f2bf(a) | ((unsigned int)f2bf(b) << 16);
}
__device__ inline bf16x8 cvt8(float4 a, float4 b) {
    bf16x8 r;
    r[0]=(short)f2bf(a.x); r[1]=(short)f2bf(a.y); r[2]=(short)f2bf(a.z); r[3]=(short)f2bf(a.w);
    r[4]=(short)f2bf(b.x); r[5]=(short)f2bf(b.y); r[6]=(short)f2bf(b.z); r[7]=(short)f2bf(b.w);
    return r;
}

// ---------------- fp32 -> bf16 casts (8 elems/thread) ----------------
__global__ __launch_bounds__(256)
void cast_x(const float* __restrict__ in, unsigned short* __restrict__ out) {
    const int i = blockIdx.x * 256 + threadIdx.x;      // i < 524288
    float4 a = ((const float4*)in)[2*i], b = ((const float4*)in)[2*i + 1];
    ((bf16x8*)out)[i] = cvt8(a, b);
}
__global__ __launch_bounds__(256)
void cast_w(const float* __restrict__ W0, const float* __restrict__ W1,
            const float* __restrict__ W2, const float* __restrict__ W3,
            unsigned short* __restrict__ o0, unsigned short* __restrict__ o1,
            unsigned short* __restrict__ o2, unsigned short* __restrict__ o3) {
    const int blk = blockIdx.x, sec = blk >> 9;        // 512 blocks per matrix
    const float* in = (sec == 0) ? W0 : (sec == 1) ? W1 : (sec == 2) ? W2 : W3;
    unsigned short* out = (sec == 0) ? o0 : (sec == 1) ? o1 : (sec == 2) ? o2 : o3;
    const int i = (blk & 511) * 256 + threadIdx.x;     // i < 131072
    float4 a = ((const float4*)in)[2*i], b = ((const float4*)in)[2*i + 1];
    ((bf16x8*)out)[i] = cvt8(a, b);
}

// ---------------- bf16 GEMM-NT (pre-cast inputs) ----------------
// TYPE 0: A = x(bf16), W sections = Wq/Wk/Wv(bf16). Epilogue: Q -> RoPE *
//         (0.125*log2e) -> (b,h,t,d); K -> RoPE -> (b,h,t,d); V -> (b,h,d,t).
// TYPE 1: A = ab(bf16), W0 = Wo(bf16), out fp32 MxN.
template<int TYPE>
__global__ __launch_bounds__(256)
void gemm_k(const unsigned short* __restrict__ A, const unsigned short* __restrict__ W0,
            const unsigned short* __restrict__ W1, const unsigned short* __restrict__ W2,
            const float* __restrict__ cs, const float* __restrict__ sn,
            unsigned short* __restrict__ qb, unsigned short* __restrict__ kb,
            unsigned short* __restrict__ vtb, float* __restrict__ fout) {
    __shared__ unsigned short As[128*64];
    __shared__ unsigned short Bs[128*64];
    const int tid = threadIdx.x;
    const int w = tid >> 6, lane = tid & 63;
    const int u = lane >> 4, c = lane & 15;
    const int bm = blockIdx.x * 128, bn = blockIdx.y * 128;
    const int wm = (w & 1) * 64, wn = (w >> 1) * 64;
    const int srow = tid >> 3, scol = (tid & 7) << 3;

    const unsigned short* Wsec;
    int wrowbase;
    if constexpr (TYPE == 0) {
        const int sec = bn >> 10;
        Wsec = (sec == 0) ? W0 : ((sec == 1) ? W1 : W2);
        wrowbase = bn & 1023;
    } else {
        Wsec = W0;
        wrowbase = bn;
    }
    const unsigned short* Wp = Wsec + (size_t)(wrowbase + srow) * K_ + scol;
    const unsigned short* Ap = A + (size_t)(bm + srow) * K_ + scol;

    f32x4 acc[4][4] = {};
    bf16x8 ra[4], rb[4];

    auto loadin = [&](int k0) {
        #pragma unroll
        for (int i = 0; i < 4; ++i) {
            ra[i] = *(const bf16x8*)(Ap + (size_t)i * 32 * K_ + k0);
            rb[i] = *(const bf16x8*)(Wp + (size_t)i * 32 * K_ + k0);
        }
    };
    loadin(0);

    for (int k0 = 0; k0 < K_; k0 += 64) {
        __syncthreads();
        #pragma unroll
        for (int i = 0; i < 4; ++i) {
            const int row = i * 32 + srow;
            const int sc = (scol * 2) ^ ((row & 7) << 4);
            *(bf16x8*)((char*)As + row * 128 + sc) = ra[i];
            *(bf16x8*)((char*)Bs + row * 128 + sc) = rb[i];
        }
        __syncthreads();
        if (k0 < K_ - 64) loadin(k0 + 64);
        #pragma unroll
        for (int kk = 0; kk < 2; ++kk) {
            bf16x8 af[4], bfr[4];
            #pragma unroll
            for (int mi = 0; mi < 4; ++mi) {
                const int row = wm + mi * 16 + c;
                const int sc = (kk * 64 + u * 16) ^ ((row & 7) << 4);
                af[mi] = *(const bf16x8*)((char*)As + row * 128 + sc);
            }
            #pragma unroll
            for (int ni = 0; ni < 4; ++ni) {
                const int row = wn + ni * 16 + c;
                const int sc = (kk * 64 + u * 16) ^ ((row & 7) << 4);
                bfr[ni] = *(const bf16x8*)((char*)Bs + row * 128 + sc);
            }
            #pragma unroll
            for (int mi = 0; mi < 4; ++mi)
                #pragma unroll
                for (int ni = 0; ni < 4; ++ni)
                    acc[mi][ni] = __builtin_amdgcn_mfma_f32_16x16x32_bf16(
                        af[mi], bfr[ni], acc[mi][ni], 0, 0, 0);
        }
    }

    if constexpr (TYPE == 1) {
        #pragma unroll
        for (int mi = 0; mi < 4; ++mi)
            #pragma unroll
            for (int ni = 0; ni < 4; ++ni)
                #pragma unroll
                for (int r = 0; r < 4; ++r)
                    fout[(size_t)(bm + wm + 16*mi + 4*u + r) * HID_ + (bn + wn + 16*ni + c)] =
                        acc[mi][ni][r];
    } else {
        const int sec = bn >> 10;
        const int h = ((bn + wn) & 1023) >> 6;
        if (sec == 2) {
            #pragma unroll
            for (int mi = 0; mi < 4; ++mi)
                #pragma unroll
                for (int r = 0; r < 4; ++r) {
                    const int mg = bm + wm + 16*mi + 4*u + r;
                    const int bb = mg >> 11, t = mg & 2047;
                    #pragma unroll
                    for (int ni = 0; ni < 4; ++ni)
                        vtb[((size_t)(bb*16 + h) * 64 + 16*ni + c) * 2048 + t] =
                            f2bf(acc[mi][ni][r]);
                }
        } else {
            unsigned short* ob = sec ? kb : qb;
            const float qsc = sec ? 1.0f : (0.125f * LOG2E);   // q in log2 domain
            #pragma unroll
            for (int mi = 0; mi < 4; ++mi)
                #pragma unroll
                for (int r = 0; r < 4; ++r) {
                    const int mg = bm + wm + 16*mi + 4*u + r;
                    const int bb = mg >> 11, t = mg & 2047;
                    const size_t base = ((size_t)(bb*16 + h) * 2048 + t) * 64;
                    #pragma unroll
                    for (int ni = 0; ni < 2; ++ni) {
                        const int dlo = 16*ni + c;
                        const float cv = cs[t*64 + dlo], sv = sn[t*64 + dlo];
                        const float Aa = acc[mi][ni][r], Bb = acc[mi][ni+2][r];
                        ob[base + dlo]      = f2bf((Aa*cv - Bb*sv) * qsc);
                        ob[base + dlo + 32] = f2bf((Bb*cv + Aa*sv) * qsc);
                    }
                }
        }
    }
}

// ---------------- 32x32 swapped-MFMA flash attention, paired q-blocks ----------------
// Block = 4 waves; handles qblk (63-j) then (j) sequentially => 65 subtiles/block,
// uniform across the whole grid (no tail). Wave w takes subtiles w, w+4, ... of each
// phase with its own online-softmax partial; partials merged in LDS per phase.
// Scores arrive in log2 domain (q pre-scaled); exp = raw v_exp_f32.
__global__ __launch_bounds__(256, 4)
void attn5(const unsigned short* __restrict__ q, const unsigned short* __restrict__ k,
           const unsigned short* __restrict__ vt, unsigned short* __restrict__ ab) {
    const int raw = blockIdx.x;
    const int bh    = (raw & 7) + 8 * ((raw >> 3) & 3);   // same-bh -> same XCD
    const int pairj = raw >> 5;
    const int tid = threadIdx.x;
    const int wid = tid >> 6, lane = tid & 63;
    const int h = lane >> 5, c = lane & 31;
    const bool hi = (h != 0);
    const int b = bh >> 4, hh = bh & 15;
    const unsigned short* qp = q  + (size_t)bh * T_ * 64;
    const unsigned short* kp = k  + (size_t)bh * T_ * 64;
    const unsigned short* vp = vt + (size_t)bh * 64 * T_;

    __shared__ float OS[4][32 * 68];
    __shared__ float mS[4][32], lS[4][32];

    auto phase = [&](int qblk) {
        const int q0 = qblk * 32;
        bf16x8 qf[4];
        #pragma unroll
        for (int s = 0; s < 4; ++s)
            qf[s] = *(const bf16x8*)(qp + (size_t)(q0 + c) * 64 + s * 16 + 8 * h);

        f32x16 O0 = {}, O1 = {};
        float m = -1e30f, lsum = 0.f;
        const int nst = qblk + 1;

        auto loadKV = [&](bf16x8 (&kf)[4], bf16x8 (&vf)[4], int st) {
            const int kvs = st << 5;
            #pragma unroll
            for (int s = 0; s < 4; ++s)
                kf[s] = *(const bf16x8*)(kp + (size_t)(kvs + c) * 64 + s * 16 + 8 * h);
            #pragma unroll
            for (int s = 0; s < 4; ++s)
                vf[s] = *(const bf16x8*)(vp + (size_t)(((s >> 1) << 5) + c) * T_
                                            + kvs + ((s & 1) << 4) + 8 * h);
        };

        auto process = [&](const bf16x8 (&kf)[4], const bf16x8 (&vf)[4], int st) {
            const int kvs = st << 5;
            f32x16 sa = {};
            #pragma unroll
            for (int s = 0; s < 4; ++s)
                sa = __builtin_amdgcn_mfma_f32_32x32x16_bf16(kf[s], qf[s], sa, 0, 0, 0);
            float p[16];
            const bool diag = (st == qblk);
            #pragma unroll
            for (int r = 0; r < 16; ++r) {
                float sv = sa[r];
                if (diag) {
                    const int kk = kvs + (r & 3) + 8 * (r >> 2) + 4 * h;
                    if (kk > q0 + c) sv = -1e30f;
                }
                p[r] = sv;
            }
            float mx = fmaxf(p[0], p[1]);
            #pragma unroll
            for (int r = 2; r < 16; ++r) mx = fmaxf(mx, p[r]);
            mx = fmaxf(mx, __shfl_xor(mx, 32));
            if (!__all(mx <= m + 8.0f)) {      // log2-domain defer threshold
                const float mn = fmaxf(m, mx);
                const float f = __builtin_amdgcn_exp2f(m - mn);
                m = mn;
                lsum *= f;
                #pragma unroll
                for (int r = 0; r < 16; ++r) { O0[r] *= f; O1[r] *= f; }
            }
            float ps = 0.f;
            #pragma unroll
            for (int r = 0; r < 16; ++r) {
                p[r] = __builtin_amdgcn_exp2f(p[r] - m);
                ps += p[r];
            }
            lsum += ps;
            unsigned o0 = pk2(p[0], p[1]),   o1 = pk2(p[2], p[3]);
            unsigned o2 = pk2(p[4], p[5]),   o3 = pk2(p[6], p[7]);
            unsigned o4 = pk2(p[8], p[9]),   o5 = pk2(p[10], p[11]);
            unsigned o6 = pk2(p[12], p[13]), o7 = pk2(p[14], p[15]);
            unsigned x0 = __shfl_xor(o0, 32), x1 = __shfl_xor(o1, 32);
            unsigned x2 = __shfl_xor(o2, 32), x3 = __shfl_xor(o3, 32);
            unsigned x4 = __shfl_xor(o4, 32), x5 = __shfl_xor(o5, 32);
            unsigned x6 = __shfl_xor(o6, 32), x7 = __shfl_xor(o7, 32);
            u32x4 B0w = { hi ? x2 : o0, hi ? x3 : o1, hi ? o2 : x0, hi ? o3 : x1 };
            u32x4 B1w = { hi ? x6 : o4, hi ? x7 : o5, hi ? o6 : x4, hi ? o7 : x5 };
            bf16x8 PB0 = __builtin_bit_cast(bf16x8, B0w);
            bf16x8 PB1 = __builtin_bit_cast(bf16x8, B1w);
            O0 = __builtin_amdgcn_mfma_f32_32x32x16_bf16(vf[0], PB0, O0, 0, 0, 0);
            O0 = __builtin_amdgcn_mfma_f32_32x32x16_bf16(vf[1], PB1, O0, 0, 0, 0);
            O1 = __builtin_amdgcn_mfma_f32_32x32x16_bf16(vf[2], PB0, O1, 0, 0, 0);
            O1 = __builtin_amdgcn_mfma_f32_32x32x16_bf16(vf[3], PB1, O1, 0, 0, 0);
        };

        bf16x8 kA[4], kB[4], vA[4], vB[4];
        if (wid < nst) loadKV(kA, vA, wid);
        for (int st = wid; st < nst; st += 8) {
            if (st + 4 < nst) loadKV(kB, vB, st + 4);
            process(kA, vA, st);
            if (st + 4 >= nst) break;
            if (st + 8 < nst) loadKV(kA, vA, st + 8);
            process(kB, vB, st + 4);
        }
        lsum += __shfl_xor(lsum, 32);

        __syncthreads();   // previous phase's merge reads complete
        if (h == 0) { mS[wid][c] = m; lS[wid][c] = lsum; }
        float* os = &OS[wid][0];
        #pragma unroll
        for (int j = 0; j < 4; ++j) {
            f32x4 t0 = { O0[4*j], O0[4*j+1], O0[4*j+2], O0[4*j+3] };
            f32x4 t1 = { O1[4*j], O1[4*j+1], O1[4*j+2], O1[4*j+3] };
            *(f32x4*)&os[c * 68 + 8*j + 4*h]      = t0;
            *(f32x4*)&os[c * 68 + 32 + 8*j + 4*h] = t1;
        }
        __syncthreads();

        const int ql = tid & 31, d0 = (tid >> 5) * 8;
        const float M = fmaxf(fmaxf(mS[0][ql], mS[1][ql]), fmaxf(mS[2][ql], mS[3][ql]));
        float acc[8] = {};
        float L = 0.f;
        #pragma unroll
        for (int w2 = 0; w2 < 4; ++w2) {
            const float sc = __builtin_amdgcn_exp2f(mS[w2][ql] - M);
            L += lS[w2][ql] * sc;
            f32x4 a = *(f32x4*)&OS[w2][ql * 68 + d0];
            f32x4 b2 = *(f32x4*)&OS[w2][ql * 68 + d0 + 4];
            #pragma unroll
            for (int t = 0; t < 4; ++t) {
                acc[t]     += a[t]  * sc;
                acc[4 + t] += b2[t] * sc;
            }
        }
        const float inv = 1.0f / L;
        uint4 ov;
        ov.x = pk2(acc[0]*inv, acc[1]*inv);
        ov.y = pk2(acc[2]*inv, acc[3]*inv);
        ov.z = pk2(acc[4]*inv, acc[5]*inv);
        ov.w = pk2(acc[6]*inv, acc[7]*inv);
        *(uint4*)(ab + ((size_t)(b * T_) + q0 + ql) * HID_ + hh * 64 + d0) = ov;
    };

    phase(63 - pairj);   // heavy half
    phase(pairj);        // light half
}

extern "C" void kernel_launch(void* const* d_in, const int* in_sizes, int n_in,
                              void* d_out, int out_size, void* d_ws, size_t ws_size,
                              hipStream_t stream) {
    const float* x  = (const float*)d_in[0];
    const float* Wq = (const float*)d_in[1];
    const float* Wk = (const float*)d_in[2];
    const float* Wv = (const float*)d_in[3];
    const float* Wo = (const float*)d_in[4];
    const float* cs = (const float*)d_in[5];
    const float* sn = (const float*)d_in[6];
    char* wsb = (char*)d_ws;
    unsigned short* xb  = (unsigned short*)(wsb);                  // 8 MB
    unsigned short* wqb = (unsigned short*)(wsb + (8u  << 20));    // 2 MB each
    unsigned short* wkb = (unsigned short*)(wsb + (10u << 20));
    unsigned short* wvb = (unsigned short*)(wsb + (12u << 20));
    unsigned short* wob = (unsigned short*)(wsb + (14u << 20));
    unsigned short* qb  = (unsigned short*)(wsb + (16u << 20));
    unsigned short* kb  = (unsigned short*)(wsb + (24u << 20));
    unsigned short* vtb = (unsigned short*)(wsb + (32u << 20));
    unsigned short* ab  = (unsigned short*)(wsb + (40u << 20));

    cast_x<<<2048, 256, 0, stream>>>(x, xb);
    cast_w<<<2048, 256, 0, stream>>>(Wq, Wk, Wv, Wo, wqb, wkb, wvb, wob);

    gemm_k<0><<<dim3(M_/128, 3072/128), 256, 0, stream>>>(
        xb, wqb, wkb, wvb, cs, sn, qb, kb, vtb, nullptr);
    attn5<<<1024, 256, 0, stream>>>(qb, kb, vtb, ab);
    gemm_k<1><<<dim3(M_/128, HID_/128), 256, 0, stream>>>(
        ab, wob, nullptr, nullptr, nullptr, nullptr,
        nullptr, nullptr, nullptr, (float*)d_out);
}

// Round 8
// 134.619 us; speedup vs baseline: 1.2382x; 1.2382x over previous
//
#include <hip/hip_runtime.h>
#include <hip/hip_bf16.h>

#define B_   2
#define T_   2048
#define HID_ 1024
#define NH_  16
#define HD_  64
#define K_   1024
#define M_   (B_*T_)

typedef __attribute__((ext_vector_type(8)))  short bf16x8;
typedef __attribute__((ext_vector_type(4)))  float f32x4;
typedef __attribute__((ext_vector_type(16))) float f32x16;
typedef __attribute__((ext_vector_type(4)))  unsigned int u32x4;

#define LOG2E 1.44269504088896340736f

__device__ inline unsigned short f2bf(float f) {
    __hip_bfloat16 h = __float2bfloat16(f);
    return __builtin_bit_cast(unsigned short, h);
}
__device__ inline float bf2f(unsigned short u) {
    return __builtin_bit_cast(float, (unsigned int)u << 16);
}
__device__ inline unsigned int pk2(float a, float b) {
    return (unsigned int)f2bf(a) | ((unsigned int)f2bf(b) << 16);
}
__device__ inline bf16x8 cvt8(float4 a, float4 b) {
    bf16x8 r;
    r[0]=(short)f2bf(a.x); r[1]=(short)f2bf(a.y); r[2]=(short)f2bf(a.z); r[3]=(short)f2bf(a.w);
    r[4]=(short)f2bf(b.x); r[5]=(short)f2bf(b.y); r[6]=(short)f2bf(b.z); r[7]=(short)f2bf(b.w);
    return r;
}

// ---------------- fp32 -> bf16 casts (8 elems/thread) ----------------
__global__ __launch_bounds__(256)
void cast_x(const float* __restrict__ in, unsigned short* __restrict__ out) {
    const int i = blockIdx.x * 256 + threadIdx.x;      // i < 524288
    float4 a = ((const float4*)in)[2*i], b = ((const float4*)in)[2*i + 1];
    ((bf16x8*)out)[i] = cvt8(a, b);
}
__global__ __launch_bounds__(256)
void cast_w(const float* __restrict__ W0, const float* __restrict__ W1,
            const float* __restrict__ W2, const float* __restrict__ W3,
            unsigned short* __restrict__ o0, unsigned short* __restrict__ o1,
            unsigned short* __restrict__ o2, unsigned short* __restrict__ o3) {
    const int blk = blockIdx.x, sec = blk >> 9;        // 512 blocks per matrix
    const float* in = (sec == 0) ? W0 : (sec == 1) ? W1 : (sec == 2) ? W2 : W3;
    unsigned short* out = (sec == 0) ? o0 : (sec == 1) ? o1 : (sec == 2) ? o2 : o3;
    const int i = (blk & 511) * 256 + threadIdx.x;     // i < 131072
    float4 a = ((const float4*)in)[2*i], b = ((const float4*)in)[2*i + 1];
    ((bf16x8*)out)[i] = cvt8(a, b);
}

// ---------------- bf16 GEMM-NT (pre-cast inputs) ----------------
// TYPE 0: A = x(bf16), W sections = Wq/Wk/Wv(bf16). Epilogue: Q -> RoPE *
//         (0.125*log2e) -> (b,h,t,d); K -> RoPE -> (b,h,t,d); V -> (b,h,d,t).
// TYPE 1: A = ab(bf16), W0 = Wo(bf16), out fp32 MxN.
template<int TYPE>
__global__ __launch_bounds__(256)
void gemm_k(const unsigned short* __restrict__ A, const unsigned short* __restrict__ W0,
            const unsigned short* __restrict__ W1, const unsigned short* __restrict__ W2,
            const float* __restrict__ cs, const float* __restrict__ sn,
            unsigned short* __restrict__ qb, unsigned short* __restrict__ kb,
            unsigned short* __restrict__ vtb, float* __restrict__ fout) {
    __shared__ unsigned short As[128*64];
    __shared__ unsigned short Bs[128*64];
    const int tid = threadIdx.x;
    const int w = tid >> 6, lane = tid & 63;
    const int u = lane >> 4, c = lane & 15;
    const int bm = blockIdx.x * 128, bn = blockIdx.y * 128;
    const int wm = (w & 1) * 64, wn = (w >> 1) * 64;
    const int srow = tid >> 3, scol = (tid & 7) << 3;

    const unsigned short* Wsec;
    int wrowbase;
    if constexpr (TYPE == 0) {
        const int sec = bn >> 10;
        Wsec = (sec == 0) ? W0 : ((sec == 1) ? W1 : W2);
        wrowbase = bn & 1023;
    } else {
        Wsec = W0;
        wrowbase = bn;
    }
    const unsigned short* Wp = Wsec + (size_t)(wrowbase + srow) * K_ + scol;
    const unsigned short* Ap = A + (size_t)(bm + srow) * K_ + scol;

    f32x4 acc[4][4] = {};
    bf16x8 ra[4], rb[4];

    auto loadin = [&](int k0) {
        #pragma unroll
        for (int i = 0; i < 4; ++i) {
            ra[i] = *(const bf16x8*)(Ap + (size_t)i * 32 * K_ + k0);
            rb[i] = *(const bf16x8*)(Wp + (size_t)i * 32 * K_ + k0);
        }
    };
    loadin(0);

    for (int k0 = 0; k0 < K_; k0 += 64) {
        __syncthreads();
        #pragma unroll
        for (int i = 0; i < 4; ++i) {
            const int row = i * 32 + srow;
            const int sc = (scol * 2) ^ ((row & 7) << 4);
            *(bf16x8*)((char*)As + row * 128 + sc) = ra[i];
            *(bf16x8*)((char*)Bs + row * 128 + sc) = rb[i];
        }
        __syncthreads();
        if (k0 < K_ - 64) loadin(k0 + 64);
        #pragma unroll
        for (int kk = 0; kk < 2; ++kk) {
            bf16x8 af[4], bfr[4];
            #pragma unroll
            for (int mi = 0; mi < 4; ++mi) {
                const int row = wm + mi * 16 + c;
                const int sc = (kk * 64 + u * 16) ^ ((row & 7) << 4);
                af[mi] = *(const bf16x8*)((char*)As + row * 128 + sc);
            }
            #pragma unroll
            for (int ni = 0; ni < 4; ++ni) {
                const int row = wn + ni * 16 + c;
                const int sc = (kk * 64 + u * 16) ^ ((row & 7) << 4);
                bfr[ni] = *(const bf16x8*)((char*)Bs + row * 128 + sc);
            }
            #pragma unroll
            for (int mi = 0; mi < 4; ++mi)
                #pragma unroll
                for (int ni = 0; ni < 4; ++ni)
                    acc[mi][ni] = __builtin_amdgcn_mfma_f32_16x16x32_bf16(
                        af[mi], bfr[ni], acc[mi][ni], 0, 0, 0);
        }
    }

    if constexpr (TYPE == 1) {
        #pragma unroll
        for (int mi = 0; mi < 4; ++mi)
            #pragma unroll
            for (int ni = 0; ni < 4; ++ni)
                #pragma unroll
                for (int r = 0; r < 4; ++r)
                    fout[(size_t)(bm + wm + 16*mi + 4*u + r) * HID_ + (bn + wn + 16*ni + c)] =
                        acc[mi][ni][r];
    } else {
        const int sec = bn >> 10;
        const int h = ((bn + wn) & 1023) >> 6;
        if (sec == 2) {
            #pragma unroll
            for (int mi = 0; mi < 4; ++mi)
                #pragma unroll
                for (int r = 0; r < 4; ++r) {
                    const int mg = bm + wm + 16*mi + 4*u + r;
                    const int bb = mg >> 11, t = mg & 2047;
                    #pragma unroll
                    for (int ni = 0; ni < 4; ++ni)
                        vtb[((size_t)(bb*16 + h) * 64 + 16*ni + c) * 2048 + t] =
                            f2bf(acc[mi][ni][r]);
                }
        } else {
            unsigned short* ob = sec ? kb : qb;
            const float qsc = sec ? 1.0f : (0.125f * LOG2E);   // q in log2 domain
            #pragma unroll
            for (int mi = 0; mi < 4; ++mi)
                #pragma unroll
                for (int r = 0; r < 4; ++r) {
                    const int mg = bm + wm + 16*mi + 4*u + r;
                    const int bb = mg >> 11, t = mg & 2047;
                    const size_t base = ((size_t)(bb*16 + h) * 2048 + t) * 64;
                    #pragma unroll
                    for (int ni = 0; ni < 2; ++ni) {
                        const int dlo = 16*ni + c;
                        const float cv = cs[t*64 + dlo], sv = sn[t*64 + dlo];
                        const float Aa = acc[mi][ni][r], Bb = acc[mi][ni+2][r];
                        ob[base + dlo]      = f2bf((Aa*cv - Bb*sv) * qsc);
                        ob[base + dlo + 32] = f2bf((Bb*cv + Aa*sv) * qsc);
                    }
                }
        }
    }
}

// ---------------- 32x32 swapped-MFMA flash attention, paired q-blocks ----------------
// Block = 4 waves; handles qblk (63-j) then (j) sequentially => 65 subtiles/block,
// uniform grid (no tail). NO register cap: the K/V double buffer needs ~104 VGPR;
// capping to 64 (R7) spilled to scratch and cost +50% (FETCH 12->61 MB).
__global__ __launch_bounds__(256)
void attn6(const unsigned short* __restrict__ q, const unsigned short* __restrict__ k,
           const unsigned short* __restrict__ vt, unsigned short* __restrict__ ab) {
    const int raw = blockIdx.x;
    const int bh    = (raw & 7) + 8 * ((raw >> 3) & 3);   // same-bh -> same XCD
    const int pairj = raw >> 5;
    const int tid = threadIdx.x;
    const int wid = tid >> 6, lane = tid & 63;
    const int h = lane >> 5, c = lane & 31;
    const bool hi = (h != 0);
    const int b = bh >> 4, hh = bh & 15;
    const unsigned short* qp = q  + (size_t)bh * T_ * 64;
    const unsigned short* kp = k  + (size_t)bh * T_ * 64;
    const unsigned short* vp = vt + (size_t)bh * 64 * T_;

    __shared__ float OS[4][32 * 68];
    __shared__ float mS[4][32], lS[4][32];

    auto phase = [&](int qblk) {
        const int q0 = qblk * 32;
        bf16x8 qf[4];
        #pragma unroll
        for (int s = 0; s < 4; ++s)
            qf[s] = *(const bf16x8*)(qp + (size_t)(q0 + c) * 64 + s * 16 + 8 * h);

        f32x16 O0 = {}, O1 = {};
        float m = -1e30f, lsum = 0.f;
        const int nst = qblk + 1;

        auto loadKV = [&](bf16x8 (&kf)[4], bf16x8 (&vf)[4], int st) {
            const int kvs = st << 5;
            #pragma unroll
            for (int s = 0; s < 4; ++s)
                kf[s] = *(const bf16x8*)(kp + (size_t)(kvs + c) * 64 + s * 16 + 8 * h);
            #pragma unroll
            for (int s = 0; s < 4; ++s)
                vf[s] = *(const bf16x8*)(vp + (size_t)(((s >> 1) << 5) + c) * T_
                                            + kvs + ((s & 1) << 4) + 8 * h);
        };

        auto process = [&](const bf16x8 (&kf)[4], const bf16x8 (&vf)[4], int st) {
            const int kvs = st << 5;
            f32x16 sa = {};
            #pragma unroll
            for (int s = 0; s < 4; ++s)
                sa = __builtin_amdgcn_mfma_f32_32x32x16_bf16(kf[s], qf[s], sa, 0, 0, 0);
            float p[16];
            const bool diag = (st == qblk);
            #pragma unroll
            for (int r = 0; r < 16; ++r) {
                float sv = sa[r];
                if (diag) {
                    const int kk = kvs + (r & 3) + 8 * (r >> 2) + 4 * h;
                    if (kk > q0 + c) sv = -1e30f;
                }
                p[r] = sv;
            }
            float mx = fmaxf(p[0], p[1]);
            #pragma unroll
            for (int r = 2; r < 16; ++r) mx = fmaxf(mx, p[r]);
            mx = fmaxf(mx, __shfl_xor(mx, 32));
            if (!__all(mx <= m + 8.0f)) {      // log2-domain defer threshold
                const float mn = fmaxf(m, mx);
                const float f = __builtin_amdgcn_exp2f(m - mn);
                m = mn;
                lsum *= f;
                #pragma unroll
                for (int r = 0; r < 16; ++r) { O0[r] *= f; O1[r] *= f; }
            }
            float ps = 0.f;
            #pragma unroll
            for (int r = 0; r < 16; ++r) {
                p[r] = __builtin_amdgcn_exp2f(p[r] - m);
                ps += p[r];
            }
            lsum += ps;
            unsigned o0 = pk2(p[0], p[1]),   o1 = pk2(p[2], p[3]);
            unsigned o2 = pk2(p[4], p[5]),   o3 = pk2(p[6], p[7]);
            unsigned o4 = pk2(p[8], p[9]),   o5 = pk2(p[10], p[11]);
            unsigned o6 = pk2(p[12], p[13]), o7 = pk2(p[14], p[15]);
            unsigned x0 = __shfl_xor(o0, 32), x1 = __shfl_xor(o1, 32);
            unsigned x2 = __shfl_xor(o2, 32), x3 = __shfl_xor(o3, 32);
            unsigned x4 = __shfl_xor(o4, 32), x5 = __shfl_xor(o5, 32);
            unsigned x6 = __shfl_xor(o6, 32), x7 = __shfl_xor(o7, 32);
            u32x4 B0w = { hi ? x2 : o0, hi ? x3 : o1, hi ? o2 : x0, hi ? o3 : x1 };
            u32x4 B1w = { hi ? x6 : o4, hi ? x7 : o5, hi ? o6 : x4, hi ? o7 : x5 };
            bf16x8 PB0 = __builtin_bit_cast(bf16x8, B0w);
            bf16x8 PB1 = __builtin_bit_cast(bf16x8, B1w);
            O0 = __builtin_amdgcn_mfma_f32_32x32x16_bf16(vf[0], PB0, O0, 0, 0, 0);
            O0 = __builtin_amdgcn_mfma_f32_32x32x16_bf16(vf[1], PB1, O0, 0, 0, 0);
            O1 = __builtin_amdgcn_mfma_f32_32x32x16_bf16(vf[2], PB0, O1, 0, 0, 0);
            O1 = __builtin_amdgcn_mfma_f32_32x32x16_bf16(vf[3], PB1, O1, 0, 0, 0);
        };

        bf16x8 kA[4], kB[4], vA[4], vB[4];
        if (wid < nst) loadKV(kA, vA, wid);
        for (int st = wid; st < nst; st += 8) {
            if (st + 4 < nst) loadKV(kB, vB, st + 4);
            process(kA, vA, st);
            if (st + 4 >= nst) break;
            if (st + 8 < nst) loadKV(kA, vA, st + 8);
            process(kB, vB, st + 4);
        }
        lsum += __shfl_xor(lsum, 32);

        __syncthreads();   // previous phase's merge reads complete
        if (h == 0) { mS[wid][c] = m; lS[wid][c] = lsum; }
        float* os = &OS[wid][0];
        #pragma unroll
        for (int j = 0; j < 4; ++j) {
            f32x4 t0 = { O0[4*j], O0[4*j+1], O0[4*j+2], O0[4*j+3] };
            f32x4 t1 = { O1[4*j], O1[4*j+1], O1[4*j+2], O1[4*j+3] };
            *(f32x4*)&os[c * 68 + 8*j + 4*h]      = t0;
            *(f32x4*)&os[c * 68 + 32 + 8*j + 4*h] = t1;
        }
        __syncthreads();

        const int ql = tid & 31, d0 = (tid >> 5) * 8;
        const float M = fmaxf(fmaxf(mS[0][ql], mS[1][ql]), fmaxf(mS[2][ql], mS[3][ql]));
        float acc[8] = {};
        float L = 0.f;
        #pragma unroll
        for (int w2 = 0; w2 < 4; ++w2) {
            const float sc = __builtin_amdgcn_exp2f(mS[w2][ql] - M);
            L += lS[w2][ql] * sc;
            f32x4 a = *(f32x4*)&OS[w2][ql * 68 + d0];
            f32x4 b2 = *(f32x4*)&OS[w2][ql * 68 + d0 + 4];
            #pragma unroll
            for (int t = 0; t < 4; ++t) {
                acc[t]     += a[t]  * sc;
                acc[4 + t] += b2[t] * sc;
            }
        }
        const float inv = 1.0f / L;
        uint4 ov;
        ov.x = pk2(acc[0]*inv, acc[1]*inv);
        ov.y = pk2(acc[2]*inv, acc[3]*inv);
        ov.z = pk2(acc[4]*inv, acc[5]*inv);
        ov.w = pk2(acc[6]*inv, acc[7]*inv);
        *(uint4*)(ab + ((size_t)(b * T_) + q0 + ql) * HID_ + hh * 64 + d0) = ov;
    };

    phase(63 - pairj);   // heavy half
    phase(pairj);        // light half
}

extern "C" void kernel_launch(void* const* d_in, const int* in_sizes, int n_in,
                              void* d_out, int out_size, void* d_ws, size_t ws_size,
                              hipStream_t stream) {
    const float* x  = (const float*)d_in[0];
    const float* Wq = (const float*)d_in[1];
    const float* Wk = (const float*)d_in[2];
    const float* Wv = (const float*)d_in[3];
    const float* Wo = (const float*)d_in[4];
    const float* cs = (const float*)d_in[5];
    const float* sn = (const float*)d_in[6];
    char* wsb = (char*)d_ws;
    unsigned short* xb  = (unsigned short*)(wsb);                  // 8 MB
    unsigned short* wqb = (unsigned short*)(wsb + (8u  << 20));    // 2 MB each
    unsigned short* wkb = (unsigned short*)(wsb + (10u << 20));
    unsigned short* wvb = (unsigned short*)(wsb + (12u << 20));
    unsigned short* wob = (unsigned short*)(wsb + (14u << 20));
    unsigned short* qb  = (unsigned short*)(wsb + (16u << 20));
    unsigned short* kb  = (unsigned short*)(wsb + (24u << 20));
    unsigned short* vtb = (unsigned short*)(wsb + (32u << 20));
    unsigned short* ab  = (unsigned short*)(wsb + (40u << 20));

    cast_x<<<2048, 256, 0, stream>>>(x, xb);
    cast_w<<<2048, 256, 0, stream>>>(Wq, Wk, Wv, Wo, wqb, wkb, wvb, wob);

    gemm_k<0><<<dim3(M_/128, 3072/128), 256, 0, stream>>>(
        xb, wqb, wkb, wvb, cs, sn, qb, kb, vtb, nullptr);
    attn6<<<1024, 256, 0, stream>>>(qb, kb, vtb, ab);
    gemm_k<1><<<dim3(M_/128, HID_/128), 256, 0, stream>>>(
        ab, wob, nullptr, nullptr, nullptr, nullptr,
        nullptr, nullptr, nullptr, (float*)d_out);
}

// Round 9
// 130.406 us; speedup vs baseline: 1.2782x; 1.0323x over previous
//
#include <hip/hip_runtime.h>
#include <hip/hip_bf16.h>

#define B_   2
#define T_   2048
#define HID_ 1024
#define NH_  16
#define HD_  64
#define K_   1024
#define M_   (B_*T_)

typedef __attribute__((ext_vector_type(8)))  short bf16x8;
typedef __attribute__((ext_vector_type(4)))  float f32x4;
typedef __attribute__((ext_vector_type(16))) float f32x16;
typedef __attribute__((ext_vector_type(4)))  unsigned int u32x4;
typedef __attribute__((ext_vector_type(2)))  unsigned int u32x2;

#define LOG2E 1.44269504088896340736f

__device__ inline unsigned short f2bf(float f) {
    __hip_bfloat16 h = __float2bfloat16(f);
    return __builtin_bit_cast(unsigned short, h);
}
__device__ inline unsigned int pk2(float a, float b) {
    return (unsigned int)f2bf(a) | ((unsigned int)f2bf(b) << 16);
}
// truncation pack: (a>>16) | (b & 0xffff0000) in ONE v_perm_b32
__device__ inline unsigned int pkt(float a, float b) {
    return __builtin_amdgcn_perm(__builtin_bit_cast(unsigned, a),
                                 __builtin_bit_cast(unsigned, b), 0x03020706u);
}
__device__ inline bf16x8 cvt8(float4 a, float4 b) {
    bf16x8 r;
    r[0]=(short)f2bf(a.x); r[1]=(short)f2bf(a.y); r[2]=(short)f2bf(a.z); r[3]=(short)f2bf(a.w);
    r[4]=(short)f2bf(b.x); r[5]=(short)f2bf(b.y); r[6]=(short)f2bf(b.z); r[7]=(short)f2bf(b.w);
    return r;
}

// ---------------- fp32 -> bf16 casts (8 elems/thread) ----------------
__global__ __launch_bounds__(256)
void cast_x(const float* __restrict__ in, unsigned short* __restrict__ out) {
    const int i = blockIdx.x * 256 + threadIdx.x;
    float4 a = ((const float4*)in)[2*i], b = ((const float4*)in)[2*i + 1];
    ((bf16x8*)out)[i] = cvt8(a, b);
}
__global__ __launch_bounds__(256)
void cast_w(const float* __restrict__ W0, const float* __restrict__ W1,
            const float* __restrict__ W2, const float* __restrict__ W3,
            unsigned short* __restrict__ o0, unsigned short* __restrict__ o1,
            unsigned short* __restrict__ o2, unsigned short* __restrict__ o3) {
    const int blk = blockIdx.x, sec = blk >> 9;
    const float* in = (sec == 0) ? W0 : (sec == 1) ? W1 : (sec == 2) ? W2 : W3;
    unsigned short* out = (sec == 0) ? o0 : (sec == 1) ? o1 : (sec == 2) ? o2 : o3;
    const int i = (blk & 511) * 256 + threadIdx.x;
    float4 a = ((const float4*)in)[2*i], b = ((const float4*)in)[2*i + 1];
    ((bf16x8*)out)[i] = cvt8(a, b);
}

// ---------------- bf16 GEMM-NT (pre-cast inputs; unchanged, proven) ----------------
template<int TYPE>
__global__ __launch_bounds__(256)
void gemm_k(const unsigned short* __restrict__ A, const unsigned short* __restrict__ W0,
            const unsigned short* __restrict__ W1, const unsigned short* __restrict__ W2,
            const float* __restrict__ cs, const float* __restrict__ sn,
            unsigned short* __restrict__ qb, unsigned short* __restrict__ kb,
            unsigned short* __restrict__ vtb, float* __restrict__ fout) {
    __shared__ unsigned short As[128*64];
    __shared__ unsigned short Bs[128*64];
    const int tid = threadIdx.x;
    const int w = tid >> 6, lane = tid & 63;
    const int u = lane >> 4, c = lane & 15;
    const int bm = blockIdx.x * 128, bn = blockIdx.y * 128;
    const int wm = (w & 1) * 64, wn = (w >> 1) * 64;
    const int srow = tid >> 3, scol = (tid & 7) << 3;

    const unsigned short* Wsec;
    int wrowbase;
    if constexpr (TYPE == 0) {
        const int sec = bn >> 10;
        Wsec = (sec == 0) ? W0 : ((sec == 1) ? W1 : W2);
        wrowbase = bn & 1023;
    } else {
        Wsec = W0;
        wrowbase = bn;
    }
    const unsigned short* Wp = Wsec + (size_t)(wrowbase + srow) * K_ + scol;
    const unsigned short* Ap = A + (size_t)(bm + srow) * K_ + scol;

    f32x4 acc[4][4] = {};
    bf16x8 ra[4], rb[4];

    auto loadin = [&](int k0) {
        #pragma unroll
        for (int i = 0; i < 4; ++i) {
            ra[i] = *(const bf16x8*)(Ap + (size_t)i * 32 * K_ + k0);
            rb[i] = *(const bf16x8*)(Wp + (size_t)i * 32 * K_ + k0);
        }
    };
    loadin(0);

    for (int k0 = 0; k0 < K_; k0 += 64) {
        __syncthreads();
        #pragma unroll
        for (int i = 0; i < 4; ++i) {
            const int row = i * 32 + srow;
            const int sc = (scol * 2) ^ ((row & 7) << 4);
            *(bf16x8*)((char*)As + row * 128 + sc) = ra[i];
            *(bf16x8*)((char*)Bs + row * 128 + sc) = rb[i];
        }
        __syncthreads();
        if (k0 < K_ - 64) loadin(k0 + 64);
        #pragma unroll
        for (int kk = 0; kk < 2; ++kk) {
            bf16x8 af[4], bfr[4];
            #pragma unroll
            for (int mi = 0; mi < 4; ++mi) {
                const int row = wm + mi * 16 + c;
                const int sc = (kk * 64 + u * 16) ^ ((row & 7) << 4);
                af[mi] = *(const bf16x8*)((char*)As + row * 128 + sc);
            }
            #pragma unroll
            for (int ni = 0; ni < 4; ++ni) {
                const int row = wn + ni * 16 + c;
                const int sc = (kk * 64 + u * 16) ^ ((row & 7) << 4);
                bfr[ni] = *(const bf16x8*)((char*)Bs + row * 128 + sc);
            }
            #pragma unroll
            for (int mi = 0; mi < 4; ++mi)
                #pragma unroll
                for (int ni = 0; ni < 4; ++ni)
                    acc[mi][ni] = __builtin_amdgcn_mfma_f32_16x16x32_bf16(
                        af[mi], bfr[ni], acc[mi][ni], 0, 0, 0);
        }
    }

    if constexpr (TYPE == 1) {
        #pragma unroll
        for (int mi = 0; mi < 4; ++mi)
            #pragma unroll
            for (int ni = 0; ni < 4; ++ni)
                #pragma unroll
                for (int r = 0; r < 4; ++r)
                    fout[(size_t)(bm + wm + 16*mi + 4*u + r) * HID_ + (bn + wn + 16*ni + c)] =
                        acc[mi][ni][r];
    } else {
        const int sec = bn >> 10;
        const int h = ((bn + wn) & 1023) >> 6;
        if (sec == 2) {
            #pragma unroll
            for (int mi = 0; mi < 4; ++mi)
                #pragma unroll
                for (int r = 0; r < 4; ++r) {
                    const int mg = bm + wm + 16*mi + 4*u + r;
                    const int bb = mg >> 11, t = mg & 2047;
                    #pragma unroll
                    for (int ni = 0; ni < 4; ++ni)
                        vtb[((size_t)(bb*16 + h) * 64 + 16*ni + c) * 2048 + t] =
                            f2bf(acc[mi][ni][r]);
                }
        } else {
            unsigned short* ob = sec ? kb : qb;
            const float qsc = sec ? 1.0f : (0.125f * LOG2E);   // q in log2 domain
            #pragma unroll
            for (int mi = 0; mi < 4; ++mi)
                #pragma unroll
                for (int r = 0; r < 4; ++r) {
                    const int mg = bm + wm + 16*mi + 4*u + r;
                    const int bb = mg >> 11, t = mg & 2047;
                    const size_t base = ((size_t)(bb*16 + h) * 2048 + t) * 64;
                    #pragma unroll
                    for (int ni = 0; ni < 2; ++ni) {
                        const int dlo = 16*ni + c;
                        const float cv = cs[t*64 + dlo], sv = sn[t*64 + dlo];
                        const float Aa = acc[mi][ni][r], Bb = acc[mi][ni+2][r];
                        ob[base + dlo]      = f2bf((Aa*cv - Bb*sv) * qsc);
                        ob[base + dlo + 32] = f2bf((Bb*cv + Aa*sv) * qsc);
                    }
                }
        }
    }
}

// ---------------- 32x32 swapped-MFMA flash attention, 4-wave KV-split ----------------
// One qblk per block (2048 blocks, heavy-first, XCD swizzle). Wave w takes KV
// subtiles w, w+4, ... with its own online-softmax partial; bf16-packed LDS merge.
// All hot-loop addressing: scalar subtile base + loop-invariant 32-bit lane offsets.
__global__ __launch_bounds__(256)
void attn7(const unsigned short* __restrict__ q, const unsigned short* __restrict__ k,
           const unsigned short* __restrict__ vt, unsigned short* __restrict__ ab) {
    const int raw = blockIdx.x;
    const int bh   = (raw & 7) + 8 * ((raw >> 3) & 3);   // same-bh -> same XCD
    const int qblk = 63 - (raw >> 5);                    // heavy blocks first
    const int tid = threadIdx.x;
    const int wid = tid >> 6, lane = tid & 63;
    const int h = lane >> 5, c = lane & 31;
    const bool hi = (h != 0);
    const int b = bh >> 4, hh = bh & 15;
    const int q0 = qblk * 32;
    const unsigned short* qp = q  + (size_t)bh * (T_*64);
    const unsigned short* kp = k  + (size_t)bh * (T_*64);
    const unsigned short* vp = vt + (size_t)bh * (64*T_);

    // loop-invariant per-lane element offsets (32-bit)
    const int kloff  = c * 64 + 8 * h;           // K row c, d = s*16+8h via imm
    const int vloff0 = c * 2048 + 8 * h;         // V^T rows c (s=0,1)
    const int vloff1 = vloff0 + 32 * 2048;       // V^T rows 32+c (s=2,3)

    bf16x8 qf[4];
    {
        const unsigned short* qrow = qp + (q0 + c) * 64 + 8 * h;
        #pragma unroll
        for (int s = 0; s < 4; ++s)
            qf[s] = *(const bf16x8*)(qrow + s * 16);
    }

    f32x16 O0 = {}, O1 = {};
    float m = -1e30f, lsum = 0.f;
    const int nst = qblk + 1;

    auto loadKV = [&](bf16x8 (&kf)[4], bf16x8 (&vf)[4], int st) {
        const unsigned short* kst = kp + (st << 11);   // + st*32*64
        const unsigned short* vst = vp + (st << 5);    // + st*32
        #pragma unroll
        for (int s = 0; s < 4; ++s)
            kf[s] = *(const bf16x8*)(kst + kloff + s * 16);
        vf[0] = *(const bf16x8*)(vst + vloff0);
        vf[1] = *(const bf16x8*)(vst + vloff0 + 16);
        vf[2] = *(const bf16x8*)(vst + vloff1);
        vf[3] = *(const bf16x8*)(vst + vloff1 + 16);
    };

    auto process = [&](const bf16x8 (&kf)[4], const bf16x8 (&vf)[4], int st) {
        const int kvs = st << 5;
        f32x16 sa = {};
        #pragma unroll
        for (int s = 0; s < 4; ++s)
            sa = __builtin_amdgcn_mfma_f32_32x32x16_bf16(kf[s], qf[s], sa, 0, 0, 0);
        float p[16];
        const bool diag = (st == qblk);
        #pragma unroll
        for (int r = 0; r < 16; ++r) {
            float sv = sa[r];
            if (diag) {
                const int kk = kvs + (r & 3) + 8 * (r >> 2) + 4 * h;
                if (kk > q0 + c) sv = -1e30f;
            }
            p[r] = sv;
        }
        float mx = fmaxf(p[0], p[1]);
        #pragma unroll
        for (int r = 2; r < 16; ++r) mx = fmaxf(mx, p[r]);
        mx = fmaxf(mx, __shfl_xor(mx, 32));
        if (!__all(mx <= m + 8.0f)) {      // log2-domain defer threshold
            const float mn = fmaxf(m, mx);
            const float f = __builtin_amdgcn_exp2f(m - mn);
            m = mn;
            lsum *= f;
            #pragma unroll
            for (int r = 0; r < 16; ++r) { O0[r] *= f; O1[r] *= f; }
        }
        float ps = 0.f;
        #pragma unroll
        for (int r = 0; r < 16; ++r) {
            p[r] = __builtin_amdgcn_exp2f(p[r] - m);
            ps += p[r];
        }
        lsum += ps;
        // truncation pack: 1 v_perm_b32 per pair
        unsigned o0 = pkt(p[0], p[1]),   o1 = pkt(p[2], p[3]);
        unsigned o2 = pkt(p[4], p[5]),   o3 = pkt(p[6], p[7]);
        unsigned o4 = pkt(p[8], p[9]),   o5 = pkt(p[10], p[11]);
        unsigned o6 = pkt(p[12], p[13]), o7 = pkt(p[14], p[15]);
        unsigned x0 = __shfl_xor(o0, 32), x1 = __shfl_xor(o1, 32);
        unsigned x2 = __shfl_xor(o2, 32), x3 = __shfl_xor(o3, 32);
        unsigned x4 = __shfl_xor(o4, 32), x5 = __shfl_xor(o5, 32);
        unsigned x6 = __shfl_xor(o6, 32), x7 = __shfl_xor(o7, 32);
        u32x4 B0w = { hi ? x2 : o0, hi ? x3 : o1, hi ? o2 : x0, hi ? o3 : x1 };
        u32x4 B1w = { hi ? x6 : o4, hi ? x7 : o5, hi ? o6 : x4, hi ? o7 : x5 };
        bf16x8 PB0 = __builtin_bit_cast(bf16x8, B0w);
        bf16x8 PB1 = __builtin_bit_cast(bf16x8, B1w);
        O0 = __builtin_amdgcn_mfma_f32_32x32x16_bf16(vf[0], PB0, O0, 0, 0, 0);
        O0 = __builtin_amdgcn_mfma_f32_32x32x16_bf16(vf[1], PB1, O0, 0, 0, 0);
        O1 = __builtin_amdgcn_mfma_f32_32x32x16_bf16(vf[2], PB0, O1, 0, 0, 0);
        O1 = __builtin_amdgcn_mfma_f32_32x32x16_bf16(vf[3], PB1, O1, 0, 0, 0);
    };

    bf16x8 kA[4], kB[4], vA[4], vB[4];
    if (wid < nst) loadKV(kA, vA, wid);
    for (int st = wid; st < nst; st += 8) {
        if (st + 4 < nst) loadKV(kB, vB, st + 4);
        process(kA, vA, st);
        if (st + 4 >= nst) break;
        if (st + 8 < nst) loadKV(kA, vA, st + 8);
        process(kB, vB, st + 4);
    }
    lsum += __shfl_xor(lsum, 32);

    // ---- merge the 4 wave-partials in LDS (bf16-packed, stride 34 u32) ----
    __shared__ unsigned OSu[4][32 * 34];
    __shared__ float mS[4][32], lS[4][32];
    if (h == 0) { mS[wid][c] = m; lS[wid][c] = lsum; }
    {
        unsigned* os = &OSu[wid][0];
        const int rb = c * 34 + 2 * h;
        #pragma unroll
        for (int j = 0; j < 4; ++j) {
            os[rb + 4*j]          = pk2(O0[4*j],   O0[4*j+1]);
            os[rb + 4*j + 1]      = pk2(O0[4*j+2], O0[4*j+3]);
            os[rb + 16 + 4*j]     = pk2(O1[4*j],   O1[4*j+1]);
            os[rb + 16 + 4*j + 1] = pk2(O1[4*j+2], O1[4*j+3]);
        }
    }
    __syncthreads();

    const int ql = tid & 31, ug = (tid >> 5) * 4;   // 4 u32 = 8 d per thread
    const float M = fmaxf(fmaxf(mS[0][ql], mS[1][ql]), fmaxf(mS[2][ql], mS[3][ql]));
    float acc[8] = {};
    float L = 0.f;
    #pragma unroll
    for (int w2 = 0; w2 < 4; ++w2) {
        const float sc = __builtin_amdgcn_exp2f(mS[w2][ql] - M);
        L += lS[w2][ql] * sc;
        u32x2 pa = *(u32x2*)&OSu[w2][ql * 34 + ug];
        u32x2 pb = *(u32x2*)&OSu[w2][ql * 34 + ug + 2];
        #pragma unroll
        for (int t = 0; t < 2; ++t) {
            acc[2*t]   += __builtin_bit_cast(float, pa[t] << 16) * sc;
            acc[2*t+1] += __builtin_bit_cast(float, pa[t] & 0xffff0000u) * sc;
            acc[4+2*t]   += __builtin_bit_cast(float, pb[t] << 16) * sc;
            acc[4+2*t+1] += __builtin_bit_cast(float, pb[t] & 0xffff0000u) * sc;
        }
    }
    const float inv = 1.0f / L;
    uint4 ov;
    ov.x = pk2(acc[0]*inv, acc[1]*inv);
    ov.y = pk2(acc[2]*inv, acc[3]*inv);
    ov.z = pk2(acc[4]*inv, acc[5]*inv);
    ov.w = pk2(acc[6]*inv, acc[7]*inv);
    *(uint4*)(ab + ((size_t)(b * T_) + q0 + ql) * HID_ + hh * 64 + ug * 2) = ov;
}

extern "C" void kernel_launch(void* const* d_in, const int* in_sizes, int n_in,
                              void* d_out, int out_size, void* d_ws, size_t ws_size,
                              hipStream_t stream) {
    const float* x  = (const float*)d_in[0];
    const float* Wq = (const float*)d_in[1];
    const float* Wk = (const float*)d_in[2];
    const float* Wv = (const float*)d_in[3];
    const float* Wo = (const float*)d_in[4];
    const float* cs = (const float*)d_in[5];
    const float* sn = (const float*)d_in[6];
    char* wsb = (char*)d_ws;
    unsigned short* xb  = (unsigned short*)(wsb);                  // 8 MB
    unsigned short* wqb = (unsigned short*)(wsb + (8u  << 20));    // 2 MB each
    unsigned short* wkb = (unsigned short*)(wsb + (10u << 20));
    unsigned short* wvb = (unsigned short*)(wsb + (12u << 20));
    unsigned short* wob = (unsigned short*)(wsb + (14u << 20));
    unsigned short* qb  = (unsigned short*)(wsb + (16u << 20));
    unsigned short* kb  = (unsigned short*)(wsb + (24u << 20));
    unsigned short* vtb = (unsigned short*)(wsb + (32u << 20));
    unsigned short* ab  = (unsigned short*)(wsb + (40u << 20));

    cast_x<<<2048, 256, 0, stream>>>(x, xb);
    cast_w<<<2048, 256, 0, stream>>>(Wq, Wk, Wv, Wo, wqb, wkb, wvb, wob);

    gemm_k<0><<<dim3(M_/128, 3072/128), 256, 0, stream>>>(
        xb, wqb, wkb, wvb, cs, sn, qb, kb, vtb, nullptr);
    attn7<<<2048, 256, 0, stream>>>(qb, kb, vtb, ab);
    gemm_k<1><<<dim3(M_/128, HID_/128), 256, 0, stream>>>(
        ab, wob, nullptr, nullptr, nullptr, nullptr,
        nullptr, nullptr, nullptr, (float*)d_out);
}